// Round 5
// baseline (557.585 us; speedup 1.0000x reference)
//
#include <hip/hip_runtime.h>
#include <math.h>

#define N_NODES 100000
#define N_EDGES 1600000
#define IN_F    512
#define HID     128

#define SH      8                       // nodes-per-bin shift
#define NPB     256                     // nodes per bin
#define BINS    ((N_NODES + NPB - 1) / NPB)   // 391
#define CBLK    256                     // edge-chunk blocks
#define EPB     ((N_EDGES + CBLK - 1) / CBLK) // 6250

typedef __attribute__((ext_vector_type(8))) _Float16 half8;
typedef __attribute__((ext_vector_type(2))) _Float16 half2v;
typedef __attribute__((ext_vector_type(4))) float float4v;

// ---- software e4m3 encode: x must be pre-scaled by 2^-8, pre-clamped to [-1.75, 1.75] ----
__device__ __forceinline__ unsigned int f16_to_e4m3bits(float xs) {
    _Float16 h = (_Float16)xs;
    unsigned short b = __builtin_bit_cast(unsigned short, h);
    unsigned int mag = (unsigned int)(b & 0x7fffu);
    mag = (mag + 0x3fu + ((mag >> 7) & 1u)) >> 7;   // RNE down to 8-bit (e4m3) field
    if (mag > 0x7eu) mag = 0x7eu;                   // never emit 0x7f (NaN pattern)
    return (((unsigned int)b >> 8) & 0x80u) | mag;
}

// ---------------- pass 0: W1 -> f16 transposed  +  zero sdeg ----------------
__global__ __launch_bounds__(256) void prep_kernel(const float* __restrict__ W1,
                                                   _Float16* __restrict__ W1T,
                                                   int* __restrict__ sdeg) {
    int i = blockIdx.x * 256 + threadIdx.x;
    if (i < IN_F * HID) {
        int k = i >> 7, c = i & 127;
        W1T[(size_t)c * IN_F + k] = (_Float16)W1[i];
    }
    if (i < N_NODES) sdeg[i] = 0;
}

// ---------------- pass 1: per-block LDS histogram over dst-bins + global out-degree ----------------
__global__ __launch_bounds__(256) void hist_kernel(const int* __restrict__ src,
                                                   const int* __restrict__ dst,
                                                   int* __restrict__ dbh,
                                                   int* __restrict__ sdeg) {
    __shared__ int hd[BINS];
    const int t = threadIdx.x, blk = blockIdx.x;
    for (int i = t; i < BINS; i += 256) hd[i] = 0;
    __syncthreads();
    const int e0 = blk * EPB, e1 = min(N_EDGES, e0 + EPB);
    for (int e = e0 + t; e < e1; e += 256) {
        atomicAdd(&hd[dst[e] >> SH], 1);
        atomicAdd(&sdeg[src[e]], 1);
    }
    __syncthreads();
    for (int i = t; i < BINS; i += 256)
        dbh[i * CBLK + blk] = hd[i];
}

// ---------------- pass 2a: per-bin exclusive scan over the 256 block counts ----------------
__global__ __launch_bounds__(256) void binscan_kernel(int* __restrict__ dbh,
                                                      int* __restrict__ dtot) {
    __shared__ int sh[256];
    const int b = blockIdx.x, t = threadIdx.x;
    int* arr = dbh + (size_t)b * CBLK;
    int v = arr[t];
    sh[t] = v; __syncthreads();
#pragma unroll
    for (int d = 1; d < 256; d <<= 1) {
        int u = (t >= d) ? sh[t - d] : 0;
        __syncthreads();
        sh[t] += u;
        __syncthreads();
    }
    arr[t] = sh[t] - v;               // exclusive prefix within bin
    if (t == 255) dtot[b] = sh[255];  // bin total
}

// ---------------- pass 2b: scan bin totals -> bin bases ----------------
__global__ __launch_bounds__(512) void binbase_kernel(const int* __restrict__ dtot,
                                                      int* __restrict__ dbase,
                                                      int* __restrict__ offs) {
    __shared__ int sh[512];
    const int t = threadIdx.x;
    int v = (t < BINS) ? dtot[t] : 0;
    sh[t] = v; __syncthreads();
#pragma unroll
    for (int d = 1; d < 512; d <<= 1) {
        int u = (t >= d) ? sh[t - d] : 0;
        __syncthreads();
        sh[t] += u;
        __syncthreads();
    }
    if (t < BINS) dbase[t] = sh[t] - v;
    if (t == BINS - 1) { dbase[BINS] = sh[t]; offs[N_NODES] = sh[t]; }
}

// ---------------- pass 3: scatter edges into dst-bin-sorted packed array ----------------
// packed word: (dst & 255) << 24 | src     (src < 2^17 fits)
__global__ __launch_bounds__(256) void scatter_bins_kernel(const int* __restrict__ src,
                                                           const int* __restrict__ dst,
                                                           const int* __restrict__ dbh,
                                                           const int* __restrict__ dbase,
                                                           unsigned int* __restrict__ es) {
    __shared__ int dcur[BINS];
    const int t = threadIdx.x, blk = blockIdx.x;
    for (int i = t; i < BINS; i += 256)
        dcur[i] = dbase[i] + dbh[i * CBLK + blk];
    __syncthreads();
    const int e0 = blk * EPB, e1 = min(N_EDGES, e0 + EPB);
    for (int e = e0 + t; e < e1; e += 256) {
        int d = dst[e], s = src[e];
        int p = atomicAdd(&dcur[d >> SH], 1);
        es[p] = ((unsigned int)(d & (NPB - 1)) << 24) | (unsigned int)s;
    }
}

// ---------------- pass 4: per-bin counting sort -> indeg/offs/norms/CSR ----------------
__global__ __launch_bounds__(256) void finalize_kernel(const unsigned int* __restrict__ es,
                                                       const int* __restrict__ sdeg,
                                                       const int* __restrict__ dbase,
                                                       int* __restrict__ csr, int* __restrict__ offs,
                                                       float* __restrict__ norm_dst,
                                                       float* __restrict__ norm_src) {
    __shared__ int cnt[NPB], pos[NPB];
    const int t = threadIdx.x, b = blockIdx.x;
    const int start = dbase[b], end = dbase[b + 1];
    cnt[t] = 0; __syncthreads();
    for (int k = start + t; k < end; k += 256)
        atomicAdd(&cnt[es[k] >> 24], 1);
    __syncthreads();
    const int c = cnt[t];
    pos[t] = c; __syncthreads();
#pragma unroll
    for (int d = 1; d < 256; d <<= 1) {
        int u = (t >= d) ? pos[t - d] : 0;
        __syncthreads();
        pos[t] += u;
        __syncthreads();
    }
    const int excl = pos[t] - c;
    const int node = (b << SH) + t;
    if (node < N_NODES) {
        offs[node] = start + excl;
        norm_dst[node] = rsqrtf(fmaxf((float)c, 1.0f));
        norm_src[node] = rsqrtf(fmaxf((float)sdeg[node], 1.0f));
    }
    cnt[t] = start + excl;      // reuse as scatter cursor
    __syncthreads();
    for (int k = start + t; k < end; k += 256) {
        unsigned int v = es[k];
        int p = atomicAdd(&cnt[v >> 24], 1);
        csr[p] = (int)(v & 0x00FFFFFFu);
    }
}

// ---------------- GEMM1 via MFMA f16: no LDS, no barriers, register-direct ----------------
// One 16-row tile per wave; A loaded straight from X (lane = row l16, k = quad*8..+8),
// A prefetched 2 K-steps ahead (HBM), B (W1T, L2-hot) prefetched 1 ahead.
// xw8 layout: row n is 128 bytes; PHYSICAL col (l16*8 + ct) holds LOGICAL col (ct*16 + l16).
__global__ __launch_bounds__(256) void gemm1_mfma_kernel(const float* __restrict__ X,
                                                         const _Float16* __restrict__ W1T,
                                                         const float* __restrict__ norm_src,
                                                         unsigned int* __restrict__ xw8) {
    const int t    = threadIdx.x;
    const int wave = t >> 6;
    const int lane = t & 63;
    const int quad = lane >> 4;
    const int l16  = lane & 15;
    const int wrow = blockIdx.x * 64 + wave * 16;     // this wave's 16 rows
    const int arow = wrow + l16;
    const int crow = (arow < N_NODES) ? arow : 0;     // clamp OOB loads to row 0
    const float*    xa = X   + (size_t)crow * IN_F + quad * 8;
    const _Float16* wb = W1T + (size_t)l16  * IN_F + quad * 8;

    float4v acc[8];
#pragma unroll
    for (int c = 0; c < 8; c++) acc[c] = (float4v)0.f;

    float4 A[2][2];     // two K-steps of A in flight
    half8  B[8];
    {
        const float4* p0 = reinterpret_cast<const float4*>(xa);
        A[0][0] = p0[0]; A[0][1] = p0[1];
        const float4* p1 = reinterpret_cast<const float4*>(xa + 32);
        A[1][0] = p1[0]; A[1][1] = p1[1];
#pragma unroll
        for (int ct = 0; ct < 8; ct++)
            B[ct] = *reinterpret_cast<const half8*>(wb + (size_t)(ct * 16) * IN_F);
    }

#pragma unroll
    for (int it = 0; it < 16; ++it) {
        const int cur = it & 1;
        half8 fa;
        fa[0] = (_Float16)A[cur][0].x; fa[1] = (_Float16)A[cur][0].y;
        fa[2] = (_Float16)A[cur][0].z; fa[3] = (_Float16)A[cur][0].w;
        fa[4] = (_Float16)A[cur][1].x; fa[5] = (_Float16)A[cur][1].y;
        fa[6] = (_Float16)A[cur][1].z; fa[7] = (_Float16)A[cur][1].w;
        if (it + 2 < 16) {          // prefetch A two K-steps ahead (HBM latency cover)
            const float4* p = reinterpret_cast<const float4*>(xa + (it + 2) * 32);
            A[cur][0] = p[0]; A[cur][1] = p[1];
        }
        half8 Bc[8];                // SSA copy; regalloc renames, no real movs
#pragma unroll
        for (int ct = 0; ct < 8; ct++) Bc[ct] = B[ct];
        if (it + 1 < 16) {          // prefetch B one K-step ahead (L2 latency cover)
#pragma unroll
            for (int ct = 0; ct < 8; ct++)
                B[ct] = *reinterpret_cast<const half8*>(
                    wb + (size_t)(ct * 16) * IN_F + (it + 1) * 32);
        }
#pragma unroll
        for (int ct = 0; ct < 8; ct++)
            acc[ct] = __builtin_amdgcn_mfma_f32_16x16x32_f16(fa, Bc[ct], acc[ct], 0, 0, 0);
    }

    // epilogue: scale by norm_src*2^-8, clamp, quantize to e4m3 (software), write 8 bytes/lane
    const int grow = wrow + quad * 4;
#pragma unroll
    for (int i = 0; i < 4; i++) {
        const int g = grow + i;
        if (g < N_NODES) {
            const float ss = norm_src[g] * 0.00390625f;   // fold 2^-8 into scale
            unsigned int by[8];
#pragma unroll
            for (int ct = 0; ct < 8; ct++) {
                float xs = acc[ct][i] * ss;
                xs = fminf(fmaxf(xs, -1.75f), 1.75f);     // e4m3 max 448 -> 1.75 scaled
                by[ct] = f16_to_e4m3bits(xs);
            }
            unsigned int w0 = by[0] | (by[1] << 8) | (by[2] << 16) | (by[3] << 24);
            unsigned int w1 = by[4] | (by[5] << 8) | (by[6] << 16) | (by[7] << 24);
            *reinterpret_cast<uint2*>(&xw8[(size_t)g * 32 + l16 * 2]) = make_uint2(w0, w1);
        }
    }
}

// ---------------- fused gather1 + relu + layer2 GEMV: 4 nodes per wave, 16 lanes each ----------------
// fp8 decode trick: f16bits = (b&0x80)<<8 | (b&0x7f)<<7 == fp8value * 2^-8 exactly (incl. subnormals)
__global__ __launch_bounds__(256) void gather1_kernel(
        const int* __restrict__ csr, const int* __restrict__ offs,
        const unsigned int* __restrict__ xw8, const float* __restrict__ norm_dst,
        const float* __restrict__ norm_src, const float* __restrict__ b1,
        const float* __restrict__ W2, float* __restrict__ hw2) {
    const int gw   = (blockIdx.x * blockDim.x + threadIdx.x) >> 6;  // wave id
    const int lane = threadIdx.x & 63;
    const int sub  = lane >> 4;         // which of 4 nodes in this wave
    const int l16  = lane & 15;
    const int n    = gw * 4 + sub;
    if (n >= N_NODES) return;
    const int off = offs[n], end = offs[n + 1];
    const uint2* xp = reinterpret_cast<const uint2*>(xw8);

    // accA={e0,e2} accB={e1,e3} accC={e4,e6} accD={e5,e7}  (within this lane's 8 bytes)
    half2v accA = (half2v)0, accB = (half2v)0, accC = (half2v)0, accD = (half2v)0;

#define DECADD(u, aE, aO)                                                          \
    {                                                                              \
        unsigned int _u = (u);                                                     \
        unsigned int _e = ((_u & 0x00800080u) << 8) | ((_u & 0x007f007fu) << 7);   \
        unsigned int _s = _u >> 8;                                                 \
        unsigned int _o = ((_s & 0x00800080u) << 8) | ((_s & 0x007f007fu) << 7);   \
        aE += __builtin_bit_cast(half2v, _e);                                      \
        aO += __builtin_bit_cast(half2v, _o);                                      \
    }
#define ACC8(u2) { DECADD((u2).x, accA, accB) DECADD((u2).y, accC, accD) }

    int k = off;
    for (; k + 8 <= end; k += 8) {
        int s0 = csr[k], s1 = csr[k + 1], s2 = csr[k + 2], s3 = csr[k + 3];
        int s4 = csr[k + 4], s5 = csr[k + 5], s6 = csr[k + 6], s7 = csr[k + 7];
        uint2 u0 = xp[(size_t)s0 * 16 + l16];
        uint2 u1 = xp[(size_t)s1 * 16 + l16];
        uint2 u2 = xp[(size_t)s2 * 16 + l16];
        uint2 u3 = xp[(size_t)s3 * 16 + l16];
        uint2 u4 = xp[(size_t)s4 * 16 + l16];
        uint2 u5 = xp[(size_t)s5 * 16 + l16];
        uint2 u6 = xp[(size_t)s6 * 16 + l16];
        uint2 u7 = xp[(size_t)s7 * 16 + l16];
        ACC8(u0) ACC8(u1) ACC8(u2) ACC8(u3) ACC8(u4) ACC8(u5) ACC8(u6) ACC8(u7)
    }
    for (; k + 4 <= end; k += 4) {
        int s0 = csr[k], s1 = csr[k + 1], s2 = csr[k + 2], s3 = csr[k + 3];
        uint2 u0 = xp[(size_t)s0 * 16 + l16];
        uint2 u1 = xp[(size_t)s1 * 16 + l16];
        uint2 u2 = xp[(size_t)s2 * 16 + l16];
        uint2 u3 = xp[(size_t)s3 * 16 + l16];
        ACC8(u0) ACC8(u1) ACC8(u2) ACC8(u3)
    }
    for (; k < end; ++k) {
        uint2 u = xp[(size_t)csr[k] * 16 + l16];
        ACC8(u)
    }
#undef ACC8
#undef DECADD

    float a[8];
    a[0] = (float)accA[0]; a[2] = (float)accA[1];
    a[1] = (float)accB[0]; a[3] = (float)accB[1];
    a[4] = (float)accC[0]; a[6] = (float)accC[1];
    a[5] = (float)accD[0]; a[7] = (float)accD[1];

    const float nd = norm_dst[n] * 256.0f;   // undo the 2^-8 decode scale here
    // lane owns LOGICAL cols {ct*16 + l16 : ct = 0..7} (permuted storage)
    float p0 = 0.f, p1 = 0.f;
#pragma unroll
    for (int ct = 0; ct < 8; ct++) {
        const int col = ct * 16 + l16;
        float h = fmaxf(a[ct] * nd + b1[col], 0.f);
        float2 w2v = reinterpret_cast<const float2*>(W2)[col];
        p0 += h * w2v.x;
        p1 += h * w2v.y;
    }
#pragma unroll
    for (int d = 1; d < 16; d <<= 1) {     // reduce within the 16-lane sub-group
        p0 += __shfl_xor(p0, d);
        p1 += __shfl_xor(p1, d);
    }
    if (l16 == 0) {
        float ns = norm_src[n];
        reinterpret_cast<float2*>(hw2)[n] = make_float2(p0 * ns, p1 * ns);
    }
}

// ---------------- fused gather2 + softmax: 4 nodes per wave (16 lanes each) ----------------
__global__ void gather2_softmax_kernel(
        const int* __restrict__ csr, const int* __restrict__ offs,
        const float* __restrict__ hw2, const float* __restrict__ norm_dst,
        const float* __restrict__ b2, float* __restrict__ out) {
    const int w    = (blockIdx.x * blockDim.x + threadIdx.x) >> 6;
    const int lane = threadIdx.x & 63;
    const int sub  = lane >> 4, k0 = lane & 15;
    const int n = w * 4 + sub;
    if (n >= N_NODES) return;
    const int off = offs[n], end = offs[n + 1];

    float a0 = 0.f, a1 = 0.f;
    for (int k = off + k0; k < end; k += 16) {
        int s = csr[k];
        float2 v = reinterpret_cast<const float2*>(hw2)[s];
        a0 += v.x; a1 += v.y;
    }
#pragma unroll
    for (int d = 1; d < 16; d <<= 1) {
        a0 += __shfl_xor(a0, d);
        a1 += __shfl_xor(a1, d);
    }
    if (k0 == 0) {
        float nd = norm_dst[n];
        float z0 = a0 * nd + b2[0];
        float z1 = a1 * nd + b2[1];
        float m = fmaxf(z0, z1);
        float e0 = expf(z0 - m), e1 = expf(z1 - m);
        float inv = 1.f / (e0 + e1);
        reinterpret_cast<float2*>(out)[n] = make_float2(e0 * inv, e1 * inv);
    }
}

extern "C" void kernel_launch(void* const* d_in, const int* in_sizes, int n_in,
                              void* d_out, int out_size, void* d_ws, size_t ws_size,
                              hipStream_t stream) {
    const float* X   = (const float*)d_in[0];
    const float* W1  = (const float*)d_in[1];
    const float* b1  = (const float*)d_in[2];
    const float* W2  = (const float*)d_in[3];
    const float* b2  = (const float*)d_in[4];
    const int*   src = (const int*)d_in[5];
    const int*   dst = (const int*)d_in[6];
    float* out = (float*)d_out;

    const size_t N = N_NODES;
    char* ws = (char*)d_ws;
    auto alloc = [&](size_t bytes) -> char* {
        char* p = ws;
        ws += (bytes + 15) & ~(size_t)15;
        return p;
    };
    int*          dbh      = (int*)alloc((size_t)BINS * CBLK * 4);   // 400 KB
    int*          dtot     = (int*)alloc(BINS * 4);
    int*          dbase    = (int*)alloc((BINS + 1) * 4);
    int*          sdeg     = (int*)alloc(N * 4);                     // 400 KB
    unsigned int* es       = (unsigned int*)alloc((size_t)N_EDGES * 4); // 6.4 MB
    int*          csr      = (int*)alloc((size_t)N_EDGES * 4);       // 6.4 MB
    int*          offs     = (int*)alloc((N + 1) * 4);
    float*        norm_src = (float*)alloc(N * 4);
    float*        norm_dst = (float*)alloc(N * 4);
    float*        hw2      = (float*)alloc(N * 2 * 4);
    _Float16*     W1T      = (_Float16*)alloc((size_t)IN_F * HID * 2); // 128 KB
    unsigned int* xw8      = (unsigned int*)alloc(N * (size_t)HID);    // 12.8 MB fp8

    // no memset needed: every buffer is fully written before it is read
    prep_kernel<<<(N_NODES + 255) / 256, 256, 0, stream>>>(W1, W1T, sdeg);
    hist_kernel<<<CBLK, 256, 0, stream>>>(src, dst, dbh, sdeg);
    binscan_kernel<<<BINS, 256, 0, stream>>>(dbh, dtot);
    binbase_kernel<<<1, 512, 0, stream>>>(dtot, dbase, offs);
    scatter_bins_kernel<<<CBLK, 256, 0, stream>>>(src, dst, dbh, dbase, es);
    finalize_kernel<<<BINS, 256, 0, stream>>>(es, sdeg, dbase,
                                              csr, offs, norm_dst, norm_src);
    gemm1_mfma_kernel<<<(N_NODES + 63) / 64, 256, 0, stream>>>(X, W1T, norm_src, xw8);
    gather1_kernel<<<(((N_NODES + 3) / 4) * 64 + 255) / 256, 256, 0, stream>>>(
        csr, offs, xw8, norm_dst, norm_src, b1, W2, hw2);
    gather2_softmax_kernel<<<(((int)N + 3) / 4 * 64 + 255) / 256, 256, 0, stream>>>(
        csr, offs, hw2, norm_dst, b2, out);
}

// Round 6
// 514.773 us; speedup vs baseline: 1.0832x; 1.0832x over previous
//
#include <hip/hip_runtime.h>
#include <math.h>

#define N_NODES 100000
#define N_EDGES 1600000
#define IN_F    512
#define HID     128

#define SH      8                       // nodes-per-bin shift
#define NPB     256                     // nodes per bin
#define BINS    ((N_NODES + NPB - 1) / NPB)   // 391
#define CBLK    256                     // edge-chunk blocks
#define EPB     ((N_EDGES + CBLK - 1) / CBLK) // 6250

typedef __attribute__((ext_vector_type(8))) _Float16 half8;
typedef __attribute__((ext_vector_type(2))) _Float16 half2v;
typedef __attribute__((ext_vector_type(4))) float float4v;

// ---- software e4m3 encode: x must be pre-scaled by 2^-8, pre-clamped to [-1.75, 1.75] ----
__device__ __forceinline__ unsigned int f16_to_e4m3bits(float xs) {
    _Float16 h = (_Float16)xs;
    unsigned short b = __builtin_bit_cast(unsigned short, h);
    unsigned int mag = (unsigned int)(b & 0x7fffu);
    mag = (mag + 0x3fu + ((mag >> 7) & 1u)) >> 7;   // RNE down to 8-bit (e4m3) field
    if (mag > 0x7eu) mag = 0x7eu;                   // never emit 0x7f (NaN pattern)
    return (((unsigned int)b >> 8) & 0x80u) | mag;
}

// ---------------- pass 0: W1 -> f16 transposed  +  zero sdeg ----------------
__global__ __launch_bounds__(256) void prep_kernel(const float* __restrict__ W1,
                                                   _Float16* __restrict__ W1T,
                                                   int* __restrict__ sdeg) {
    int i = blockIdx.x * 256 + threadIdx.x;
    if (i < IN_F * HID) {
        int k = i >> 7, c = i & 127;
        W1T[(size_t)c * IN_F + k] = (_Float16)W1[i];
    }
    if (i < N_NODES) sdeg[i] = 0;
}

// ---------------- pass 1: per-block LDS histogram over dst-bins + global out-degree ----------------
__global__ __launch_bounds__(256) void hist_kernel(const int* __restrict__ src,
                                                   const int* __restrict__ dst,
                                                   int* __restrict__ dbh,
                                                   int* __restrict__ sdeg) {
    __shared__ int hd[BINS];
    const int t = threadIdx.x, blk = blockIdx.x;
    for (int i = t; i < BINS; i += 256) hd[i] = 0;
    __syncthreads();
    const int e0 = blk * EPB, e1 = min(N_EDGES, e0 + EPB);
    for (int e = e0 + t; e < e1; e += 256) {
        atomicAdd(&hd[dst[e] >> SH], 1);
        atomicAdd(&sdeg[src[e]], 1);
    }
    __syncthreads();
    for (int i = t; i < BINS; i += 256)
        dbh[i * CBLK + blk] = hd[i];
}

// ---------------- pass 2a: per-bin exclusive scan over the 256 block counts ----------------
__global__ __launch_bounds__(256) void binscan_kernel(int* __restrict__ dbh,
                                                      int* __restrict__ dtot) {
    __shared__ int sh[256];
    const int b = blockIdx.x, t = threadIdx.x;
    int* arr = dbh + (size_t)b * CBLK;
    int v = arr[t];
    sh[t] = v; __syncthreads();
#pragma unroll
    for (int d = 1; d < 256; d <<= 1) {
        int u = (t >= d) ? sh[t - d] : 0;
        __syncthreads();
        sh[t] += u;
        __syncthreads();
    }
    arr[t] = sh[t] - v;               // exclusive prefix within bin
    if (t == 255) dtot[b] = sh[255];  // bin total
}

// ---------------- pass 2b: scan bin totals -> bin bases ----------------
__global__ __launch_bounds__(512) void binbase_kernel(const int* __restrict__ dtot,
                                                      int* __restrict__ dbase,
                                                      int* __restrict__ offs) {
    __shared__ int sh[512];
    const int t = threadIdx.x;
    int v = (t < BINS) ? dtot[t] : 0;
    sh[t] = v; __syncthreads();
#pragma unroll
    for (int d = 1; d < 512; d <<= 1) {
        int u = (t >= d) ? sh[t - d] : 0;
        __syncthreads();
        sh[t] += u;
        __syncthreads();
    }
    if (t < BINS) dbase[t] = sh[t] - v;
    if (t == BINS - 1) { dbase[BINS] = sh[t]; offs[N_NODES] = sh[t]; }
}

// ---------------- pass 3: scatter edges into dst-bin-sorted packed array ----------------
// packed word: (dst & 255) << 24 | src     (src < 2^17 fits)
__global__ __launch_bounds__(256) void scatter_bins_kernel(const int* __restrict__ src,
                                                           const int* __restrict__ dst,
                                                           const int* __restrict__ dbh,
                                                           const int* __restrict__ dbase,
                                                           unsigned int* __restrict__ es) {
    __shared__ int dcur[BINS];
    const int t = threadIdx.x, blk = blockIdx.x;
    for (int i = t; i < BINS; i += 256)
        dcur[i] = dbase[i] + dbh[i * CBLK + blk];
    __syncthreads();
    const int e0 = blk * EPB, e1 = min(N_EDGES, e0 + EPB);
    for (int e = e0 + t; e < e1; e += 256) {
        int d = dst[e], s = src[e];
        int p = atomicAdd(&dcur[d >> SH], 1);
        es[p] = ((unsigned int)(d & (NPB - 1)) << 24) | (unsigned int)s;
    }
}

// ---------------- pass 4: per-bin counting sort -> indeg/offs/norms/CSR ----------------
__global__ __launch_bounds__(256) void finalize_kernel(const unsigned int* __restrict__ es,
                                                       const int* __restrict__ sdeg,
                                                       const int* __restrict__ dbase,
                                                       int* __restrict__ csr, int* __restrict__ offs,
                                                       float* __restrict__ norm_dst,
                                                       float* __restrict__ norm_src) {
    __shared__ int cnt[NPB], pos[NPB];
    const int t = threadIdx.x, b = blockIdx.x;
    const int start = dbase[b], end = dbase[b + 1];
    cnt[t] = 0; __syncthreads();
    for (int k = start + t; k < end; k += 256)
        atomicAdd(&cnt[es[k] >> 24], 1);
    __syncthreads();
    const int c = cnt[t];
    pos[t] = c; __syncthreads();
#pragma unroll
    for (int d = 1; d < 256; d <<= 1) {
        int u = (t >= d) ? pos[t - d] : 0;
        __syncthreads();
        pos[t] += u;
        __syncthreads();
    }
    const int excl = pos[t] - c;
    const int node = (b << SH) + t;
    if (node < N_NODES) {
        offs[node] = start + excl;
        norm_dst[node] = rsqrtf(fmaxf((float)c, 1.0f));
        norm_src[node] = rsqrtf(fmaxf((float)sdeg[node], 1.0f));
    }
    cnt[t] = start + excl;      // reuse as scatter cursor
    __syncthreads();
    for (int k = start + t; k < end; k += 256) {
        unsigned int v = es[k];
        int p = atomicAdd(&cnt[v >> 24], 1);
        csr[p] = (int)(v & 0x00FFFFFFu);
    }
}

// ---------------- GEMM1 via MFMA f16: 64-row tile, LDS double-buffered staging ----------------
// Round-3 structure (cooperative staging restores memory-level parallelism) with the tile
// halved 128->64 rows: grid 782->1563 blocks, ~4-5 blocks/CU resident, barrier stalls covered.
// xw8 layout: row n is 128 bytes; PHYSICAL col (l16*8 + ct) holds LOGICAL col (ct*16 + l16).
#define APAD 40     // LDS row stride in f16 (32 cols + 8 pad -> 80 B stride, 2-way bank alias only)
__global__ __launch_bounds__(256) void gemm1_mfma_kernel(const float* __restrict__ X,
                                                         const _Float16* __restrict__ W1T,
                                                         const float* __restrict__ norm_src,
                                                         unsigned int* __restrict__ xw8) {
    __shared__ _Float16 As[2][64 * APAD];

    const int t    = threadIdx.x;
    const int wave = t >> 6;
    const int lane = t & 63;
    const int m0   = blockIdx.x * 64;
    const int quad = lane >> 4;
    const int l16  = lane & 15;

    float4v acc[8];
#pragma unroll
    for (int c = 0; c < 8; c++) acc[c] = (float4v)0.f;

    // staging: thread t owns row (t>>2), cols ((t&3)*8 .. +8) of the 64x32 f32 tile
    const int srow = t >> 2;
    const int scol = (t & 3) * 8;
    const int sgrow = m0 + srow;
    const bool svalid = sgrow < N_NODES;
    const float* xbase = X + (size_t)sgrow * IN_F + scol;

    float4 va[2];
    va[0] = va[1] = make_float4(0.f, 0.f, 0.f, 0.f);
    if (svalid) {
        const float4* xp = reinterpret_cast<const float4*>(xbase);
        va[0] = xp[0]; va[1] = xp[1];
    }
    half8 bfrag[8];
#pragma unroll
    for (int ct = 0; ct < 8; ct++)
        bfrag[ct] = *reinterpret_cast<const half8*>(&W1T[(size_t)(ct * 16 + l16) * IN_F + quad * 8]);

    {
        half8 h;
        h[0]=(_Float16)va[0].x; h[1]=(_Float16)va[0].y; h[2]=(_Float16)va[0].z; h[3]=(_Float16)va[0].w;
        h[4]=(_Float16)va[1].x; h[5]=(_Float16)va[1].y; h[6]=(_Float16)va[1].z; h[7]=(_Float16)va[1].w;
        *reinterpret_cast<half8*>(&As[0][srow * APAD + scol]) = h;
    }

    int cur = 0;
    for (int it = 0; it < IN_F / 32; it++) {
        const int ktn = (it + 1) * 32;
        const bool more = ktn < IN_F;
        __syncthreads();

        float4 vb[2];
        half8 bnext[8];
        if (more) {
            if (svalid) {
                const float4* xp = reinterpret_cast<const float4*>(xbase + ktn);
                vb[0] = xp[0]; vb[1] = xp[1];
            } else {
                vb[0] = vb[1] = make_float4(0.f, 0.f, 0.f, 0.f);
            }
#pragma unroll
            for (int ct = 0; ct < 8; ct++)
                bnext[ct] = *reinterpret_cast<const half8*>(
                    &W1T[(size_t)(ct * 16 + l16) * IN_F + ktn + quad * 8]);
        }

        half8 afrag = *reinterpret_cast<const half8*>(
            &As[cur][(wave * 16 + l16) * APAD + quad * 8]);
#pragma unroll
        for (int ct = 0; ct < 8; ct++)
            acc[ct] = __builtin_amdgcn_mfma_f32_16x16x32_f16(afrag, bfrag[ct], acc[ct], 0, 0, 0);

        if (more) {
            half8 h;
            h[0]=(_Float16)vb[0].x; h[1]=(_Float16)vb[0].y; h[2]=(_Float16)vb[0].z; h[3]=(_Float16)vb[0].w;
            h[4]=(_Float16)vb[1].x; h[5]=(_Float16)vb[1].y; h[6]=(_Float16)vb[1].z; h[7]=(_Float16)vb[1].w;
            *reinterpret_cast<half8*>(&As[cur ^ 1][srow * APAD + scol]) = h;
#pragma unroll
            for (int ct = 0; ct < 8; ct++) bfrag[ct] = bnext[ct];
        }
        cur ^= 1;
    }

    // epilogue: scale by norm_src*2^-8, clamp, quantize to e4m3 (software), write 8 bytes/lane
    const int grow = m0 + wave * 16 + quad * 4;
#pragma unroll
    for (int i = 0; i < 4; i++) {
        const int g = grow + i;
        if (g < N_NODES) {
            const float ss = norm_src[g] * 0.00390625f;   // fold 2^-8 into scale
            unsigned int by[8];
#pragma unroll
            for (int ct = 0; ct < 8; ct++) {
                float xs = acc[ct][i] * ss;
                xs = fminf(fmaxf(xs, -1.75f), 1.75f);     // e4m3 max 448 -> 1.75 scaled
                by[ct] = f16_to_e4m3bits(xs);
            }
            unsigned int w0 = by[0] | (by[1] << 8) | (by[2] << 16) | (by[3] << 24);
            unsigned int w1 = by[4] | (by[5] << 8) | (by[6] << 16) | (by[7] << 24);
            *reinterpret_cast<uint2*>(&xw8[(size_t)g * 32 + l16 * 2]) = make_uint2(w0, w1);
        }
    }
}

// ---------------- fused gather1 + relu + layer2 GEMV: 4 nodes per wave, 16 lanes each ----------------
// fp8 decode trick: f16bits = (b&0x80)<<8 | (b&0x7f)<<7 == fp8value * 2^-8 exactly (incl. subnormals)
__global__ __launch_bounds__(256) void gather1_kernel(
        const int* __restrict__ csr, const int* __restrict__ offs,
        const unsigned int* __restrict__ xw8, const float* __restrict__ norm_dst,
        const float* __restrict__ norm_src, const float* __restrict__ b1,
        const float* __restrict__ W2, float* __restrict__ hw2) {
    const int gw   = (blockIdx.x * blockDim.x + threadIdx.x) >> 6;  // wave id
    const int lane = threadIdx.x & 63;
    const int sub  = lane >> 4;         // which of 4 nodes in this wave
    const int l16  = lane & 15;
    const int n    = gw * 4 + sub;
    if (n >= N_NODES) return;
    const int off = offs[n], end = offs[n + 1];
    const uint2* xp = reinterpret_cast<const uint2*>(xw8);

    // accA={e0,e2} accB={e1,e3} accC={e4,e6} accD={e5,e7}  (within this lane's 8 bytes)
    half2v accA = (half2v)0, accB = (half2v)0, accC = (half2v)0, accD = (half2v)0;

#define DECADD(u, aE, aO)                                                          \
    {                                                                              \
        unsigned int _u = (u);                                                     \
        unsigned int _e = ((_u & 0x00800080u) << 8) | ((_u & 0x007f007fu) << 7);   \
        unsigned int _s = _u >> 8;                                                 \
        unsigned int _o = ((_s & 0x00800080u) << 8) | ((_s & 0x007f007fu) << 7);   \
        aE += __builtin_bit_cast(half2v, _e);                                      \
        aO += __builtin_bit_cast(half2v, _o);                                      \
    }
#define ACC8(u2) { DECADD((u2).x, accA, accB) DECADD((u2).y, accC, accD) }

    int k = off;
    for (; k + 8 <= end; k += 8) {
        int s0 = csr[k], s1 = csr[k + 1], s2 = csr[k + 2], s3 = csr[k + 3];
        int s4 = csr[k + 4], s5 = csr[k + 5], s6 = csr[k + 6], s7 = csr[k + 7];
        uint2 u0 = xp[(size_t)s0 * 16 + l16];
        uint2 u1 = xp[(size_t)s1 * 16 + l16];
        uint2 u2 = xp[(size_t)s2 * 16 + l16];
        uint2 u3 = xp[(size_t)s3 * 16 + l16];
        uint2 u4 = xp[(size_t)s4 * 16 + l16];
        uint2 u5 = xp[(size_t)s5 * 16 + l16];
        uint2 u6 = xp[(size_t)s6 * 16 + l16];
        uint2 u7 = xp[(size_t)s7 * 16 + l16];
        ACC8(u0) ACC8(u1) ACC8(u2) ACC8(u3) ACC8(u4) ACC8(u5) ACC8(u6) ACC8(u7)
    }
    for (; k + 4 <= end; k += 4) {
        int s0 = csr[k], s1 = csr[k + 1], s2 = csr[k + 2], s3 = csr[k + 3];
        uint2 u0 = xp[(size_t)s0 * 16 + l16];
        uint2 u1 = xp[(size_t)s1 * 16 + l16];
        uint2 u2 = xp[(size_t)s2 * 16 + l16];
        uint2 u3 = xp[(size_t)s3 * 16 + l16];
        ACC8(u0) ACC8(u1) ACC8(u2) ACC8(u3)
    }
    for (; k < end; ++k) {
        uint2 u = xp[(size_t)csr[k] * 16 + l16];
        ACC8(u)
    }
#undef ACC8
#undef DECADD

    float a[8];
    a[0] = (float)accA[0]; a[2] = (float)accA[1];
    a[1] = (float)accB[0]; a[3] = (float)accB[1];
    a[4] = (float)accC[0]; a[6] = (float)accC[1];
    a[5] = (float)accD[0]; a[7] = (float)accD[1];

    const float nd = norm_dst[n] * 256.0f;   // undo the 2^-8 decode scale here
    // lane owns LOGICAL cols {ct*16 + l16 : ct = 0..7} (permuted storage)
    float p0 = 0.f, p1 = 0.f;
#pragma unroll
    for (int ct = 0; ct < 8; ct++) {
        const int col = ct * 16 + l16;
        float h = fmaxf(a[ct] * nd + b1[col], 0.f);
        float2 w2v = reinterpret_cast<const float2*>(W2)[col];
        p0 += h * w2v.x;
        p1 += h * w2v.y;
    }
#pragma unroll
    for (int d = 1; d < 16; d <<= 1) {     // reduce within the 16-lane sub-group
        p0 += __shfl_xor(p0, d);
        p1 += __shfl_xor(p1, d);
    }
    if (l16 == 0) {
        float ns = norm_src[n];
        reinterpret_cast<float2*>(hw2)[n] = make_float2(p0 * ns, p1 * ns);
    }
}

// ---------------- fused gather2 + softmax: 4 nodes per wave (16 lanes each) ----------------
__global__ void gather2_softmax_kernel(
        const int* __restrict__ csr, const int* __restrict__ offs,
        const float* __restrict__ hw2, const float* __restrict__ norm_dst,
        const float* __restrict__ b2, float* __restrict__ out) {
    const int w    = (blockIdx.x * blockDim.x + threadIdx.x) >> 6;
    const int lane = threadIdx.x & 63;
    const int sub  = lane >> 4, k0 = lane & 15;
    const int n = w * 4 + sub;
    if (n >= N_NODES) return;
    const int off = offs[n], end = offs[n + 1];

    float a0 = 0.f, a1 = 0.f;
    for (int k = off + k0; k < end; k += 16) {
        int s = csr[k];
        float2 v = reinterpret_cast<const float2*>(hw2)[s];
        a0 += v.x; a1 += v.y;
    }
#pragma unroll
    for (int d = 1; d < 16; d <<= 1) {
        a0 += __shfl_xor(a0, d);
        a1 += __shfl_xor(a1, d);
    }
    if (k0 == 0) {
        float nd = norm_dst[n];
        float z0 = a0 * nd + b2[0];
        float z1 = a1 * nd + b2[1];
        float m = fmaxf(z0, z1);
        float e0 = expf(z0 - m), e1 = expf(z1 - m);
        float inv = 1.f / (e0 + e1);
        reinterpret_cast<float2*>(out)[n] = make_float2(e0 * inv, e1 * inv);
    }
}

extern "C" void kernel_launch(void* const* d_in, const int* in_sizes, int n_in,
                              void* d_out, int out_size, void* d_ws, size_t ws_size,
                              hipStream_t stream) {
    const float* X   = (const float*)d_in[0];
    const float* W1  = (const float*)d_in[1];
    const float* b1  = (const float*)d_in[2];
    const float* W2  = (const float*)d_in[3];
    const float* b2  = (const float*)d_in[4];
    const int*   src = (const int*)d_in[5];
    const int*   dst = (const int*)d_in[6];
    float* out = (float*)d_out;

    const size_t N = N_NODES;
    char* ws = (char*)d_ws;
    auto alloc = [&](size_t bytes) -> char* {
        char* p = ws;
        ws += (bytes + 15) & ~(size_t)15;
        return p;
    };
    int*          dbh      = (int*)alloc((size_t)BINS * CBLK * 4);   // 400 KB
    int*          dtot     = (int*)alloc(BINS * 4);
    int*          dbase    = (int*)alloc((BINS + 1) * 4);
    int*          sdeg     = (int*)alloc(N * 4);                     // 400 KB
    unsigned int* es       = (unsigned int*)alloc((size_t)N_EDGES * 4); // 6.4 MB
    int*          csr      = (int*)alloc((size_t)N_EDGES * 4);       // 6.4 MB
    int*          offs     = (int*)alloc((N + 1) * 4);
    float*        norm_src = (float*)alloc(N * 4);
    float*        norm_dst = (float*)alloc(N * 4);
    float*        hw2      = (float*)alloc(N * 2 * 4);
    _Float16*     W1T      = (_Float16*)alloc((size_t)IN_F * HID * 2); // 128 KB
    unsigned int* xw8      = (unsigned int*)alloc(N * (size_t)HID);    // 12.8 MB fp8

    // no memset needed: every buffer is fully written before it is read
    prep_kernel<<<(N_NODES + 255) / 256, 256, 0, stream>>>(W1, W1T, sdeg);
    hist_kernel<<<CBLK, 256, 0, stream>>>(src, dst, dbh, sdeg);
    binscan_kernel<<<BINS, 256, 0, stream>>>(dbh, dtot);
    binbase_kernel<<<1, 512, 0, stream>>>(dtot, dbase, offs);
    scatter_bins_kernel<<<CBLK, 256, 0, stream>>>(src, dst, dbh, dbase, es);
    finalize_kernel<<<BINS, 256, 0, stream>>>(es, sdeg, dbase,
                                              csr, offs, norm_dst, norm_src);
    gemm1_mfma_kernel<<<(N_NODES + 63) / 64, 256, 0, stream>>>(X, W1T, norm_src, xw8);
    gather1_kernel<<<(((N_NODES + 3) / 4) * 64 + 255) / 256, 256, 0, stream>>>(
        csr, offs, xw8, norm_dst, norm_src, b1, W2, hw2);
    gather2_softmax_kernel<<<(((int)N + 3) / 4 * 64 + 255) / 256, 256, 0, stream>>>(
        csr, offs, hw2, norm_dst, b2, out);
}

// Round 8
// 470.253 us; speedup vs baseline: 1.1857x; 1.0947x over previous
//
#include <hip/hip_runtime.h>
#include <math.h>

#define N_NODES 100000
#define N_EDGES 1600000
#define IN_F    512
#define HID     128

#define SH      8                       // nodes-per-bin shift
#define NPB     256                     // nodes per bin
#define BINS    ((N_NODES + NPB - 1) / NPB)   // 391
#define CBLK    256                     // edge-chunk blocks
#define EPB     ((N_EDGES + CBLK - 1) / CBLK) // 6250

typedef __attribute__((ext_vector_type(8))) _Float16 half8;
typedef __attribute__((ext_vector_type(2))) _Float16 half2v;
typedef __attribute__((ext_vector_type(4))) float float4v;

// ---- software e4m3 encode: x must be pre-scaled by 2^-8, pre-clamped to [-1.75, 1.75] ----
__device__ __forceinline__ unsigned int f16_to_e4m3bits(float xs) {
    _Float16 h = (_Float16)xs;
    unsigned short b = __builtin_bit_cast(unsigned short, h);
    unsigned int mag = (unsigned int)(b & 0x7fffu);
    mag = (mag + 0x3fu + ((mag >> 7) & 1u)) >> 7;   // RNE down to 8-bit (e4m3) field
    if (mag > 0x7eu) mag = 0x7eu;                   // never emit 0x7f (NaN pattern)
    return (((unsigned int)b >> 8) & 0x80u) | mag;
}

// ---------------- pass 0: W1 -> f16, K-tile-contiguous layout  +  zero sdeg ----------------
// W1S[kt][n][j] = W1[kt*32+j][n]   (kt = k/32, j = k%32, n = output col)
// so each 32-K tile of B is one contiguous 8 KB block.
__global__ __launch_bounds__(256) void prep_kernel(const float* __restrict__ W1,
                                                   _Float16* __restrict__ W1S,
                                                   int* __restrict__ sdeg) {
    int i = blockIdx.x * 256 + threadIdx.x;
    if (i < IN_F * HID) {
        int k = i >> 7, c = i & 127;
        W1S[(size_t)(k >> 5) * 4096 + c * 32 + (k & 31)] = (_Float16)W1[i];
    }
    if (i < N_NODES) sdeg[i] = 0;
}

// ---------------- pass 1: per-block LDS histogram over dst-bins + global out-degree ----------------
__global__ __launch_bounds__(256) void hist_kernel(const int* __restrict__ src,
                                                   const int* __restrict__ dst,
                                                   int* __restrict__ dbh,
                                                   int* __restrict__ sdeg) {
    __shared__ int hd[BINS];
    const int t = threadIdx.x, blk = blockIdx.x;
    for (int i = t; i < BINS; i += 256) hd[i] = 0;
    __syncthreads();
    const int e0 = blk * EPB, e1 = min(N_EDGES, e0 + EPB);
    for (int e = e0 + t; e < e1; e += 256) {
        atomicAdd(&hd[dst[e] >> SH], 1);
        atomicAdd(&sdeg[src[e]], 1);
    }
    __syncthreads();
    for (int i = t; i < BINS; i += 256)
        dbh[i * CBLK + blk] = hd[i];
}

// ---------------- pass 2a: per-bin exclusive scan over the 256 block counts ----------------
__global__ __launch_bounds__(256) void binscan_kernel(int* __restrict__ dbh,
                                                      int* __restrict__ dtot) {
    __shared__ int sh[256];
    const int b = blockIdx.x, t = threadIdx.x;
    int* arr = dbh + (size_t)b * CBLK;
    int v = arr[t];
    sh[t] = v; __syncthreads();
#pragma unroll
    for (int d = 1; d < 256; d <<= 1) {
        int u = (t >= d) ? sh[t - d] : 0;
        __syncthreads();
        sh[t] += u;
        __syncthreads();
    }
    arr[t] = sh[t] - v;               // exclusive prefix within bin
    if (t == 255) dtot[b] = sh[255];  // bin total
}

// ---------------- pass 2b: scan bin totals -> bin bases ----------------
__global__ __launch_bounds__(512) void binbase_kernel(const int* __restrict__ dtot,
                                                      int* __restrict__ dbase,
                                                      int* __restrict__ offs) {
    __shared__ int sh[512];
    const int t = threadIdx.x;
    int v = (t < BINS) ? dtot[t] : 0;
    sh[t] = v; __syncthreads();
#pragma unroll
    for (int d = 1; d < 512; d <<= 1) {
        int u = (t >= d) ? sh[t - d] : 0;
        __syncthreads();
        sh[t] += u;
        __syncthreads();
    }
    if (t < BINS) dbase[t] = sh[t] - v;
    if (t == BINS - 1) { dbase[BINS] = sh[t]; offs[N_NODES] = sh[t]; }
}

// ---------------- pass 3: scatter edges into dst-bin-sorted packed array ----------------
// packed word: (dst & 255) << 24 | src     (src < 2^17 fits)
__global__ __launch_bounds__(256) void scatter_bins_kernel(const int* __restrict__ src,
                                                           const int* __restrict__ dst,
                                                           const int* __restrict__ dbh,
                                                           const int* __restrict__ dbase,
                                                           unsigned int* __restrict__ es) {
    __shared__ int dcur[BINS];
    const int t = threadIdx.x, blk = blockIdx.x;
    for (int i = t; i < BINS; i += 256)
        dcur[i] = dbase[i] + dbh[i * CBLK + blk];
    __syncthreads();
    const int e0 = blk * EPB, e1 = min(N_EDGES, e0 + EPB);
    for (int e = e0 + t; e < e1; e += 256) {
        int d = dst[e], s = src[e];
        int p = atomicAdd(&dcur[d >> SH], 1);
        es[p] = ((unsigned int)(d & (NPB - 1)) << 24) | (unsigned int)s;
    }
}

// ---------------- pass 4: per-bin counting sort -> indeg/offs/norms/CSR ----------------
__global__ __launch_bounds__(256) void finalize_kernel(const unsigned int* __restrict__ es,
                                                       const int* __restrict__ sdeg,
                                                       const int* __restrict__ dbase,
                                                       int* __restrict__ csr, int* __restrict__ offs,
                                                       float* __restrict__ norm_dst,
                                                       float* __restrict__ norm_src) {
    __shared__ int cnt[NPB], pos[NPB];
    const int t = threadIdx.x, b = blockIdx.x;
    const int start = dbase[b], end = dbase[b + 1];
    cnt[t] = 0; __syncthreads();
    for (int k = start + t; k < end; k += 256)
        atomicAdd(&cnt[es[k] >> 24], 1);
    __syncthreads();
    const int c = cnt[t];
    pos[t] = c; __syncthreads();
#pragma unroll
    for (int d = 1; d < 256; d <<= 1) {
        int u = (t >= d) ? pos[t - d] : 0;
        __syncthreads();
        pos[t] += u;
        __syncthreads();
    }
    const int excl = pos[t] - c;
    const int node = (b << SH) + t;
    if (node < N_NODES) {
        offs[node] = start + excl;
        norm_dst[node] = rsqrtf(fmaxf((float)c, 1.0f));
        norm_src[node] = rsqrtf(fmaxf((float)sdeg[node], 1.0f));
    }
    cnt[t] = start + excl;      // reuse as scatter cursor
    __syncthreads();
    for (int k = start + t; k < end; k += 256) {
        unsigned int v = es[k];
        int p = atomicAdd(&cnt[v >> 24], 1);
        csr[p] = (int)(v & 0x00FFFFFFu);
    }
}

// ---------------- GEMM1 via MFMA f16: 64-row tile, A AND B double-buffered in LDS ----------------
// B-fix: waves previously re-loaded all B-fragments from global every K-step as 16-B requests
// 16 KB apart (64 lines/wave-instr -> TA address-rate bound). Now B is staged per-iter from the
// K-tile-contiguous W1S (8 KB fully-linear, 32 B/thread) and fragments come from LDS.
// xw8 layout: row n is 128 bytes; PHYSICAL col (l16*8 + ct) holds LOGICAL col (ct*16 + l16).
#define AP 40       // LDS row stride (f16) for A: 32 cols + 8 pad
#define BP 40       // LDS row stride (f16) for B: 32 k + 8 pad (2-way bank alias only)
__global__ __launch_bounds__(256) void gemm1_mfma_kernel(const float* __restrict__ X,
                                                         const _Float16* __restrict__ W1S,
                                                         const float* __restrict__ norm_src,
                                                         unsigned int* __restrict__ xw8) {
    __shared__ _Float16 As[2][64 * AP];     // 10240 B
    __shared__ _Float16 Bs[2][128 * BP];    // 20480 B

    const int t    = threadIdx.x;
    const int wave = t >> 6;
    const int lane = t & 63;
    const int m0   = blockIdx.x * 64;
    const int quad = lane >> 4;
    const int l16  = lane & 15;

    float4v acc[8];
#pragma unroll
    for (int c = 0; c < 8; c++) acc[c] = (float4v)0.f;

    // A staging: thread t owns row (t>>2), cols ((t&3)*8 .. +8) of the 64x32 f32 tile
    const int srow = t >> 2;
    const int scol = (t & 3) * 8;
    const int sgrow = m0 + srow;
    const bool svalid = sgrow < N_NODES;
    const float* xbase = X + (size_t)sgrow * IN_F + scol;
    // B staging: thread t reads 16 f16 at W1S[kt*4096 + t*16] -> Bs[t>>1][(t&1)*16 ..]
    const int boff = (t >> 1) * BP + (t & 1) * 16;

    {   // prologue: stage tile 0
        float4 va[2];
        va[0] = va[1] = make_float4(0.f, 0.f, 0.f, 0.f);
        if (svalid) {
            const float4* xp = reinterpret_cast<const float4*>(xbase);
            va[0] = xp[0]; va[1] = xp[1];
        }
        half8 b0 = *reinterpret_cast<const half8*>(&W1S[t * 16]);
        half8 b1 = *reinterpret_cast<const half8*>(&W1S[t * 16 + 8]);
        half8 h;
        h[0]=(_Float16)va[0].x; h[1]=(_Float16)va[0].y; h[2]=(_Float16)va[0].z; h[3]=(_Float16)va[0].w;
        h[4]=(_Float16)va[1].x; h[5]=(_Float16)va[1].y; h[6]=(_Float16)va[1].z; h[7]=(_Float16)va[1].w;
        *reinterpret_cast<half8*>(&As[0][srow * AP + scol]) = h;
        *reinterpret_cast<half8*>(&Bs[0][boff])     = b0;
        *reinterpret_cast<half8*>(&Bs[0][boff + 8]) = b1;
    }

    int cur = 0;
    for (int it = 0; it < IN_F / 32; it++) {
        const int ktn = (it + 1) * 32;
        const bool more = ktn < IN_F;
        __syncthreads();

        float4 vb[2];
        half8 nb0, nb1;
        if (more) {
            if (svalid) {
                const float4* xp = reinterpret_cast<const float4*>(xbase + ktn);
                vb[0] = xp[0]; vb[1] = xp[1];
            } else {
                vb[0] = vb[1] = make_float4(0.f, 0.f, 0.f, 0.f);
            }
            nb0 = *reinterpret_cast<const half8*>(&W1S[(size_t)ktn * 128 + t * 16]);
            nb1 = *reinterpret_cast<const half8*>(&W1S[(size_t)ktn * 128 + t * 16 + 8]);
        }

        half8 afrag = *reinterpret_cast<const half8*>(
            &As[cur][(wave * 16 + l16) * AP + quad * 8]);
        half8 bf[8];
#pragma unroll
        for (int ct = 0; ct < 8; ct++)
            bf[ct] = *reinterpret_cast<const half8*>(
                &Bs[cur][(ct * 16 + l16) * BP + quad * 8]);
#pragma unroll
        for (int ct = 0; ct < 8; ct++)
            acc[ct] = __builtin_amdgcn_mfma_f32_16x16x32_f16(afrag, bf[ct], acc[ct], 0, 0, 0);

        if (more) {
            half8 h;
            h[0]=(_Float16)vb[0].x; h[1]=(_Float16)vb[0].y; h[2]=(_Float16)vb[0].z; h[3]=(_Float16)vb[0].w;
            h[4]=(_Float16)vb[1].x; h[5]=(_Float16)vb[1].y; h[6]=(_Float16)vb[1].z; h[7]=(_Float16)vb[1].w;
            *reinterpret_cast<half8*>(&As[cur ^ 1][srow * AP + scol]) = h;
            *reinterpret_cast<half8*>(&Bs[cur ^ 1][boff])     = nb0;
            *reinterpret_cast<half8*>(&Bs[cur ^ 1][boff + 8]) = nb1;
        }
        cur ^= 1;
    }

    // epilogue: scale by norm_src*2^-8, clamp, quantize to e4m3 (software), write 8 bytes/lane
    const int grow = m0 + wave * 16 + quad * 4;
#pragma unroll
    for (int i = 0; i < 4; i++) {
        const int g = grow + i;
        if (g < N_NODES) {
            const float ss = norm_src[g] * 0.00390625f;   // fold 2^-8 into scale
            unsigned int by[8];
#pragma unroll
            for (int ct = 0; ct < 8; ct++) {
                float xs = acc[ct][i] * ss;
                xs = fminf(fmaxf(xs, -1.75f), 1.75f);     // e4m3 max 448 -> 1.75 scaled
                by[ct] = f16_to_e4m3bits(xs);
            }
            unsigned int w0 = by[0] | (by[1] << 8) | (by[2] << 16) | (by[3] << 24);
            unsigned int w1 = by[4] | (by[5] << 8) | (by[6] << 16) | (by[7] << 24);
            *reinterpret_cast<uint2*>(&xw8[(size_t)g * 32 + l16 * 2]) = make_uint2(w0, w1);
        }
    }
}

// ---------------- fused gather1 + relu + layer2 GEMV: 4 nodes per wave, 16 lanes each ----------------
// fp8 decode trick: f16bits = (b&0x80)<<8 | (b&0x7f)<<7 == fp8value * 2^-8 exactly (incl. subnormals)
__global__ __launch_bounds__(256) void gather1_kernel(
        const int* __restrict__ csr, const int* __restrict__ offs,
        const unsigned int* __restrict__ xw8, const float* __restrict__ norm_dst,
        const float* __restrict__ norm_src, const float* __restrict__ b1,
        const float* __restrict__ W2, float* __restrict__ hw2) {
    const int gw   = (blockIdx.x * blockDim.x + threadIdx.x) >> 6;  // wave id
    const int lane = threadIdx.x & 63;
    const int sub  = lane >> 4;         // which of 4 nodes in this wave
    const int l16  = lane & 15;
    const int n    = gw * 4 + sub;
    if (n >= N_NODES) return;
    const int off = offs[n], end = offs[n + 1];
    const uint2* xp = reinterpret_cast<const uint2*>(xw8);

    // accA={e0,e2} accB={e1,e3} accC={e4,e6} accD={e5,e7}  (within this lane's 8 bytes)
    half2v accA = (half2v)0, accB = (half2v)0, accC = (half2v)0, accD = (half2v)0;

#define DECADD(u, aE, aO)                                                          \
    {                                                                              \
        unsigned int _u = (u);                                                     \
        unsigned int _e = ((_u & 0x00800080u) << 8) | ((_u & 0x007f007fu) << 7);   \
        unsigned int _s = _u >> 8;                                                 \
        unsigned int _o = ((_s & 0x00800080u) << 8) | ((_s & 0x007f007fu) << 7);   \
        aE += __builtin_bit_cast(half2v, _e);                                      \
        aO += __builtin_bit_cast(half2v, _o);                                      \
    }
#define ACC8(u2) { DECADD((u2).x, accA, accB) DECADD((u2).y, accC, accD) }

    int k = off;
    for (; k + 8 <= end; k += 8) {
        int s0 = csr[k], s1 = csr[k + 1], s2 = csr[k + 2], s3 = csr[k + 3];
        int s4 = csr[k + 4], s5 = csr[k + 5], s6 = csr[k + 6], s7 = csr[k + 7];
        uint2 u0 = xp[(size_t)s0 * 16 + l16];
        uint2 u1 = xp[(size_t)s1 * 16 + l16];
        uint2 u2 = xp[(size_t)s2 * 16 + l16];
        uint2 u3 = xp[(size_t)s3 * 16 + l16];
        uint2 u4 = xp[(size_t)s4 * 16 + l16];
        uint2 u5 = xp[(size_t)s5 * 16 + l16];
        uint2 u6 = xp[(size_t)s6 * 16 + l16];
        uint2 u7 = xp[(size_t)s7 * 16 + l16];
        ACC8(u0) ACC8(u1) ACC8(u2) ACC8(u3) ACC8(u4) ACC8(u5) ACC8(u6) ACC8(u7)
    }
    for (; k + 4 <= end; k += 4) {
        int s0 = csr[k], s1 = csr[k + 1], s2 = csr[k + 2], s3 = csr[k + 3];
        uint2 u0 = xp[(size_t)s0 * 16 + l16];
        uint2 u1 = xp[(size_t)s1 * 16 + l16];
        uint2 u2 = xp[(size_t)s2 * 16 + l16];
        uint2 u3 = xp[(size_t)s3 * 16 + l16];
        ACC8(u0) ACC8(u1) ACC8(u2) ACC8(u3)
    }
    for (; k < end; ++k) {
        uint2 u = xp[(size_t)csr[k] * 16 + l16];
        ACC8(u)
    }
#undef ACC8
#undef DECADD

    float a[8];
    a[0] = (float)accA[0]; a[2] = (float)accA[1];
    a[1] = (float)accB[0]; a[3] = (float)accB[1];
    a[4] = (float)accC[0]; a[6] = (float)accC[1];
    a[5] = (float)accD[0]; a[7] = (float)accD[1];

    const float nd = norm_dst[n] * 256.0f;   // undo the 2^-8 decode scale here
    // lane owns LOGICAL cols {ct*16 + l16 : ct = 0..7} (permuted storage)
    float p0 = 0.f, p1 = 0.f;
#pragma unroll
    for (int ct = 0; ct < 8; ct++) {
        const int col = ct * 16 + l16;
        float h = fmaxf(a[ct] * nd + b1[col], 0.f);
        float2 w2v = reinterpret_cast<const float2*>(W2)[col];
        p0 += h * w2v.x;
        p1 += h * w2v.y;
    }
#pragma unroll
    for (int d = 1; d < 16; d <<= 1) {     // reduce within the 16-lane sub-group
        p0 += __shfl_xor(p0, d);
        p1 += __shfl_xor(p1, d);
    }
    if (l16 == 0) {
        float ns = norm_src[n];
        reinterpret_cast<float2*>(hw2)[n] = make_float2(p0 * ns, p1 * ns);
    }
}

// ---------------- fused gather2 + softmax: 4 nodes per wave (16 lanes each) ----------------
__global__ void gather2_softmax_kernel(
        const int* __restrict__ csr, const int* __restrict__ offs,
        const float* __restrict__ hw2, const float* __restrict__ norm_dst,
        const float* __restrict__ b2, float* __restrict__ out) {
    const int w    = (blockIdx.x * blockDim.x + threadIdx.x) >> 6;
    const int lane = threadIdx.x & 63;
    const int sub  = lane >> 4, k0 = lane & 15;
    const int n = w * 4 + sub;
    if (n >= N_NODES) return;
    const int off = offs[n], end = offs[n + 1];

    float a0 = 0.f, a1 = 0.f;
    for (int k = off + k0; k < end; k += 16) {
        int s = csr[k];
        float2 v = reinterpret_cast<const float2*>(hw2)[s];
        a0 += v.x; a1 += v.y;
    }
#pragma unroll
    for (int d = 1; d < 16; d <<= 1) {
        a0 += __shfl_xor(a0, d);
        a1 += __shfl_xor(a1, d);
    }
    if (k0 == 0) {
        float nd = norm_dst[n];
        float z0 = a0 * nd + b2[0];
        float z1 = a1 * nd + b2[1];
        float m = fmaxf(z0, z1);
        float e0 = expf(z0 - m), e1 = expf(z1 - m);
        float inv = 1.f / (e0 + e1);
        reinterpret_cast<float2*>(out)[n] = make_float2(e0 * inv, e1 * inv);
    }
}

extern "C" void kernel_launch(void* const* d_in, const int* in_sizes, int n_in,
                              void* d_out, int out_size, void* d_ws, size_t ws_size,
                              hipStream_t stream) {
    const float* X   = (const float*)d_in[0];
    const float* W1  = (const float*)d_in[1];
    const float* b1  = (const float*)d_in[2];
    const float* W2  = (const float*)d_in[3];
    const float* b2  = (const float*)d_in[4];
    const int*   src = (const int*)d_in[5];
    const int*   dst = (const int*)d_in[6];
    float* out = (float*)d_out;

    const size_t N = N_NODES;
    char* ws = (char*)d_ws;
    auto alloc = [&](size_t bytes) -> char* {
        char* p = ws;
        ws += (bytes + 15) & ~(size_t)15;
        return p;
    };
    int*          dbh      = (int*)alloc((size_t)BINS * CBLK * 4);   // 400 KB
    int*          dtot     = (int*)alloc(BINS * 4);
    int*          dbase    = (int*)alloc((BINS + 1) * 4);
    int*          sdeg     = (int*)alloc(N * 4);                     // 400 KB
    unsigned int* es       = (unsigned int*)alloc((size_t)N_EDGES * 4); // 6.4 MB
    int*          csr      = (int*)alloc((size_t)N_EDGES * 4);       // 6.4 MB
    int*          offs     = (int*)alloc((N + 1) * 4);
    float*        norm_src = (float*)alloc(N * 4);
    float*        norm_dst = (float*)alloc(N * 4);
    float*        hw2      = (float*)alloc(N * 2 * 4);
    _Float16*     W1S      = (_Float16*)alloc((size_t)IN_F * HID * 2); // 128 KB
    unsigned int* xw8      = (unsigned int*)alloc(N * (size_t)HID);    // 12.8 MB fp8

    // no memset needed: every buffer is fully written before it is read
    prep_kernel<<<(N_NODES + 255) / 256, 256, 0, stream>>>(W1, W1S, sdeg);
    hist_kernel<<<CBLK, 256, 0, stream>>>(src, dst, dbh, sdeg);
    binscan_kernel<<<BINS, 256, 0, stream>>>(dbh, dtot);
    binbase_kernel<<<1, 512, 0, stream>>>(dtot, dbase, offs);
    scatter_bins_kernel<<<CBLK, 256, 0, stream>>>(src, dst, dbh, dbase, es);
    finalize_kernel<<<BINS, 256, 0, stream>>>(es, sdeg, dbase,
                                              csr, offs, norm_dst, norm_src);
    gemm1_mfma_kernel<<<(N_NODES + 63) / 64, 256, 0, stream>>>(X, W1S, norm_src, xw8);
    gather1_kernel<<<(((N_NODES + 3) / 4) * 64 + 255) / 256, 256, 0, stream>>>(
        csr, offs, xw8, norm_dst, norm_src, b1, W2, hw2);
    gather2_softmax_kernel<<<(((int)N + 3) / 4 * 64 + 255) / 256, 256, 0, stream>>>(
        csr, offs, hw2, norm_dst, b2, out);
}